// Round 1
// baseline (421.395 us; speedup 1.0000x reference)
//
#include <hip/hip_runtime.h>

#define EMBED_PER_TYPE 128
#define EMBED_DIM 768
#define ROWS_PER_BLOCK 4

// One wave (64 lanes) per output row. Row layout: 768 floats = 192 float4.
// Lane j handles float4 slots {j, j+64, j+128}: slot s -> segment s>>5,
// offset-in-segment s&31. Segment source rows are wave-uniform (row % k),
// so the only lane-varying select is lo-half vs hi-half of the wave.
__global__ __launch_bounds__(256) void smart_embedding_kernel(
    const float* __restrict__ price_w,
    const float* __restrict__ size_w,
    const float* __restrict__ exchange_w,
    const float* __restrict__ pair_w,
    const float* __restrict__ level_w,
    const float* __restrict__ time_w,
    const int* __restrict__ nf_ptr,
    float* __restrict__ out)
{
    const int nf = *nf_ptr;                 // tiny scalar load, L2-hit
    const int tid  = threadIdx.x;
    const int wave = tid >> 6;
    const int lane = tid & 63;
    const unsigned row = blockIdx.x * ROWS_PER_BLOCK + wave;
    if (row >= (unsigned)nf) return;

    // Wave-uniform source-row base pointers for the 6 segments.
    const float* bases[6];
    bases[0] = price_w;                                        // broadcast row 0
    bases[1] = size_w;                                         // broadcast row 0
    bases[2] = exchange_w + (row % 3u)  * EMBED_PER_TYPE;
    bases[3] = pair_w     + (row % 7u)  * EMBED_PER_TYPE;
    bases[4] = level_w    + (row % 15u) * EMBED_PER_TYPE;
    bases[5] = time_w     + (row % 31u) * EMBED_PER_TYPE;

    float* __restrict__ orow = out + (size_t)row * EMBED_DIM;
    const int off = (lane & 31) * 4;        // float offset within a segment
    const bool hi = (lane >= 32);

#pragma unroll
    for (int k = 0; k < 3; ++k) {
        const float* base = hi ? bases[2 * k + 1] : bases[2 * k];
        float4 v = *reinterpret_cast<const float4*>(base + off);      // L1-resident table read
        *reinterpret_cast<float4*>(orow + (k * 64 + lane) * 4) = v;   // coalesced 16B store
    }
}

extern "C" void kernel_launch(void* const* d_in, const int* in_sizes, int n_in,
                              void* d_out, int out_size, void* d_ws, size_t ws_size,
                              hipStream_t stream) {
    const float* price_w    = (const float*)d_in[0];
    const float* size_w     = (const float*)d_in[1];
    const float* exchange_w = (const float*)d_in[2];
    const float* pair_w     = (const float*)d_in[3];
    const float* level_w    = (const float*)d_in[4];
    const float* time_w     = (const float*)d_in[5];
    const int*   nf_ptr     = (const int*)d_in[6];
    float* out = (float*)d_out;

    const int rows = out_size / EMBED_DIM;               // = num_features
    const int blocks = (rows + ROWS_PER_BLOCK - 1) / ROWS_PER_BLOCK;

    smart_embedding_kernel<<<blocks, 256, 0, stream>>>(
        price_w, size_w, exchange_w, pair_w, level_w, time_w, nf_ptr, out);
}

// Round 3
// 406.177 us; speedup vs baseline: 1.0375x; 1.0375x over previous
//
#include <hip/hip_runtime.h>

#define ROW_F4 192   // 768 floats = 192 float4 per output row
#define CHUNK  16    // rows per wave

typedef float v4f __attribute__((ext_vector_type(4)));  // native vector: OK for nontemporal builtins

// One wave = 16 consecutive rows. Lane layout per row (192 float4 slots):
//   slot = k*64 + lane, k in {0,1,2}; lane<32 -> segment 2k, lane>=32 -> 2k+1.
// k=0 (price|size) is row-invariant -> held in a register, stores never wait.
// k=1 (exchange%3 | pair%7) and k=2 (level%15 | time%31) use incremental
// per-lane row counters (2 VALU per row each) instead of magic-divide mods.
__global__ __launch_bounds__(256) void smart_embedding_kernel(
    const v4f* __restrict__ price_w,
    const v4f* __restrict__ size_w,
    const v4f* __restrict__ exchange_w,   // each table row = 32 float4
    const v4f* __restrict__ pair_w,
    const v4f* __restrict__ level_w,
    const v4f* __restrict__ time_w,
    v4f* __restrict__ out,
    int rows)
{
    const int tid  = threadIdx.x;
    const int wave = tid >> 6;
    const int lane = tid & 63;
    const int off  = lane & 31;          // float4 slot within a 128-float segment
    const bool hi  = lane >= 32;

    int r0 = (blockIdx.x * 4 + wave) * CHUNK;
    if (r0 >= rows) return;
    const int rend = (r0 + CHUNK < rows) ? r0 + CHUNK : rows;

    // Row-invariant segment (k=0): price for lo half, size for hi half.
    const v4f v0 = hi ? size_w[off] : price_w[off];

    // Per-lane table base + period for k=1, k=2.
    const v4f* base1 = hi ? pair_w : exchange_w;
    const v4f* base2 = hi ? time_w : level_w;
    const int p1 = hi ? 7  : 3;
    const int p2 = hi ? 31 : 15;

    int m1 = r0 % p1;                    // one-time magic-divide, then incremental
    int m2 = r0 % p2;

    v4f* orow = out + (size_t)r0 * ROW_F4 + lane;

#pragma unroll 4
    for (int r = r0; r < rend; ++r) {
        v4f v1 = base1[m1 * 32 + off];   // L1-resident (tables total ~30 KB)
        v4f v2 = base2[m2 * 32 + off];
        __builtin_nontemporal_store(v0, orow);        // no vmcnt dependency
        __builtin_nontemporal_store(v1, orow + 64);   // imm offset 1024 B
        __builtin_nontemporal_store(v2, orow + 128);  // imm offset 2048 B
        orow += ROW_F4;
        m1 = (m1 + 1 == p1) ? 0 : m1 + 1;
        m2 = (m2 + 1 == p2) ? 0 : m2 + 1;
    }
}

extern "C" void kernel_launch(void* const* d_in, const int* in_sizes, int n_in,
                              void* d_out, int out_size, void* d_ws, size_t ws_size,
                              hipStream_t stream) {
    const v4f* price_w    = (const v4f*)d_in[0];
    const v4f* size_w     = (const v4f*)d_in[1];
    const v4f* exchange_w = (const v4f*)d_in[2];
    const v4f* pair_w     = (const v4f*)d_in[3];
    const v4f* level_w    = (const v4f*)d_in[4];
    const v4f* time_w     = (const v4f*)d_in[5];
    v4f* out = (v4f*)d_out;

    const int rows = out_size / 768;                       // = num_features
    const int blocks = (rows + 4 * CHUNK - 1) / (4 * CHUNK);  // 4 waves/block

    smart_embedding_kernel<<<blocks, 256, 0, stream>>>(
        price_w, size_w, exchange_w, pair_w, level_w, time_w, out, rows);
}